// Round 7
// baseline (761.489 us; speedup 1.0000x reference)
//
#include <hip/hip_runtime.h>
#include <math.h>

#define NB 4096
#define NN 256
#define NF 16
#define NK 64
#define DIN 19
#define DM 128
#define DFF 256

using short8  = __attribute__((ext_vector_type(8))) short;
using short4v = __attribute__((ext_vector_type(4))) short;
using f32x4   = __attribute__((ext_vector_type(4))) float;

__device__ inline f32x4 mfma32(short8 a, short8 b, f32x4 c) {
    return __builtin_amdgcn_mfma_f32_16x16x32_bf16(a, b, c, 0, 0, 0);
}
__device__ inline f32x4 mfma16(short4v a, short4v b, f32x4 c) {
    return __builtin_amdgcn_mfma_f32_16x16x16bf16_1k(a, b, c, 0, 0, 0);
}

__device__ inline ushort f2bf(float f) {
    unsigned u = __float_as_uint(f);
    return (ushort)((u + 0x7fffu + ((u >> 16) & 1u)) >> 16);
}
__device__ inline float bf2f(ushort h) {
    return __uint_as_float(((unsigned)h) << 16);
}

// ---- pre-kernel: convert + PERMUTE weights so fragment reads are contiguous ----
// Wembc: per nt (8): 64 lanes x 8 shorts; lane: n=nt*16+(lane&15), k=(lane>>4)*8+j
//        (K padded 19->32; col 31 = b_emb  [bias folded via xn col31=1.0])
// W1c:   per grp=(nt2*8+kt): 64 lanes x 4 shorts: n1=nt2*16+(lane&15), k1=kt*16+(lane>>4)*4+e
// W2c:   per grp=(nt3*16+kt3): n2=nt3*16+(lane&15), k2=kt3*16+(lane>>4)*4+e
__global__ void convert_weights(const float* __restrict__ W_emb,
                                const float* __restrict__ b_emb,
                                const float* __restrict__ W1,
                                const float* __restrict__ W2,
                                ushort* __restrict__ Wembc,
                                ushort* __restrict__ W1c,
                                ushort* __restrict__ W2c) {
    const int i = blockIdx.x * 256 + threadIdx.x;   // 0..32767
    if (i < 4096) {
        const int j = i & 7, s = i >> 3;
        const int nt = s >> 6, lane = s & 63;
        const int n = nt*16 + (lane & 15);
        const int k = (lane >> 4)*8 + j;
        float v = (k < DIN) ? W_emb[n*DIN + k] : (k == 31 ? b_emb[n] : 0.0f);
        Wembc[i] = f2bf(v);
    }
    if (i < 32768) {
        const int e = i & 3, s = i >> 2;
        const int grp = s >> 6, lane = s & 63;
        const int lr = lane & 15, lg = lane >> 4;
        const int n1 = (grp >> 3)*16 + lr;
        const int k1 = (grp & 7)*16 + lg*4 + e;
        W1c[i] = f2bf(W1[n1*DM + k1]);
        const int n2 = (grp >> 4)*16 + lr;
        const int k2 = (grp & 15)*16 + lg*4 + e;
        W2c[i] = f2bf(W2[n2*DFF + k2]);
    }
}

// ---- kernel 1: top-K select + feature build ----
__global__ __launch_bounds__(256) void select_kernel(
    const float* __restrict__ x, const int* __restrict__ idxs,
    const float* __restrict__ origin, const float* __restrict__ direction,
    const float* __restrict__ norm_count, const float* __restrict__ norm_mean,
    const float* __restrict__ norm_sqsum,
    ushort* __restrict__ xnB, float* __restrict__ outrel, float* __restrict__ outmask)
{
    __shared__ unsigned long long s_keys[NN];
    const int b = blockIdx.x;
    const int t = threadIdx.x;

    const float dirx = direction[b*2+0], diry = direction[b*2+1];
    const float ang = -atan2f(diry, dirx);
    const float cr = cosf(ang), sr = sinf(ang);
    const float ox = origin[b*2+0], oy = origin[b*2+1];

    {
        const int j = idxs[b*NN + t];
        const float4 xr = *reinterpret_cast<const float4*>(x + (size_t)j*NF);
        const float dx = xr.x - ox, dy = xr.y - oy;
        const float r0 = cr*dx - sr*dy;
        const float r1 = sr*dx + cr*dy;
        const float dist = sqrtf(r0*r0 + r1*r1);
        const float key = -dist - ((xr.z == 0.0f) ? 1e8f : 0.0f);
        unsigned u = __float_as_uint(key);
        u = (u & 0x80000000u) ? ~u : (u | 0x80000000u);
        s_keys[t] = ((unsigned long long)(~u) << 32) | (unsigned)t;
    }
    __syncthreads();

    for (int sz = 2; sz <= NN; sz <<= 1) {
        for (int st = sz >> 1; st > 0; st >>= 1) {
            const int ixj = t ^ st;
            if (ixj > t) {
                const unsigned long long a = s_keys[t];
                const unsigned long long c = s_keys[ixj];
                const bool up = ((t & sz) == 0);
                if ((a > c) == up) { s_keys[t] = c; s_keys[ixj] = a; }
            }
            __syncthreads();
        }
    }

    if (t < NK) {
        const int p = (int)(s_keys[t] & 0xFFFFFFFFull);
        const int j = idxs[b*NN + p];
        const float4* xrow = reinterpret_cast<const float4*>(x + (size_t)j*NF);
        const float4 a0 = xrow[0], a1 = xrow[1], a2 = xrow[2], a3 = xrow[3];
        float xc[DIN];
        xc[0]=a0.x; xc[1]=a0.y; xc[2]=a0.z; xc[3]=a0.w;
        xc[4]=a1.x; xc[5]=a1.y; xc[6]=a1.z; xc[7]=a1.w;
        xc[8]=a2.x; xc[9]=a2.y; xc[10]=a2.z; xc[11]=a2.w;
        xc[12]=a3.x; xc[13]=a3.y; xc[14]=a3.z; xc[15]=a3.w;
        const float dx = xc[0]-ox, dy = xc[1]-oy;
        const float r0 = cr*dx - sr*dy;
        const float r1 = sr*dx + cr*dy;
        const float dist = sqrtf(r0*r0 + r1*r1);
        const float inv = 1.0f / (dist + 1e-8f);
        xc[16] = r0*inv; xc[17] = r1*inv; xc[18] = sqrtf(dist);
        const float cnt = norm_count[0];
        union { ushort us[32]; int4 v4[4]; } u;
        #pragma unroll
        for (int f = 0; f < DIN; ++f) {
            float sd = sqrtf(norm_sqsum[f] / (cnt - 1.0f));
            sd = (sd == 0.0f) ? 1.0f : sd;
            float v = (xc[f] - norm_mean[f]) / sd;
            v = fminf(fmaxf(v, -5.0f), 5.0f);
            u.us[f] = f2bf(v);
        }
        #pragma unroll
        for (int f = DIN; f < 31; ++f) u.us[f] = 0;
        u.us[31] = 0x3F80;   // 1.0 bf16 -> bias column
        int4* dst = reinterpret_cast<int4*>(xnB + ((size_t)b*NK + t)*32);
        dst[0] = u.v4[0]; dst[1] = u.v4[1]; dst[2] = u.v4[2]; dst[3] = u.v4[3];
        const bool msk = (xc[2] == 0.0f);
        outrel[((size_t)b*NK + t)*2 + 0] = r0;
        outrel[((size_t)b*NK + t)*2 + 1] = r1;
        outmask[(size_t)b*NK + t] = msk ? 1.0f : 0.0f;
    }
}

// ---- kernel 2: all-register transposed MLP; coalesced egress via LDS staging ----
// launch_bounds(512,1): 8 waves/block must co-reside -> compiler caps at 256 VGPR,
// kernel needs ~180 live -> NO SPILLS (R5/R6's (512,2) forced 128 VGPR -> GB-scale
// scratch spill traffic, the observed 723-960MB phantom FETCH).
__global__ __launch_bounds__(512, 1) void mlp_kernel(
    const float* __restrict__ b1, const float* __restrict__ b2,
    const float* __restrict__ ln1g, const float* __restrict__ ln1b,
    const float* __restrict__ ln2g, const float* __restrict__ ln2b,
    const ushort* __restrict__ Wembc, const ushort* __restrict__ W1c,
    const ushort* __restrict__ W2c, const ushort* __restrict__ xnB,
    const float* __restrict__ outmask, float* __restrict__ out)
{
    __shared__ __align__(16) ushort s_w1[32768];     // 64 KB
    __shared__ __align__(16) ushort s_w2[32768];     // 64 KB
    __shared__ __align__(16) ushort s_stage[16384];  // 32 KB: 8 waves x 4 KB private
    // total 160 KB, 1 block/CU

    const int t = threadIdx.x;
    {
        const int4* g1 = (const int4*)W1c;  int4* d1 = (int4*)s_w1;
        const int4* g2 = (const int4*)W2c;  int4* d2 = (int4*)s_w2;
        #pragma unroll
        for (int j = 0; j < 8; ++j) { d1[j*512 + t] = g1[j*512 + t];
                                      d2[j*512 + t] = g2[j*512 + t]; }
    }
    __syncthreads();

    const int wave = t >> 6, lane = t & 63;
    const int lr = lane & 15, lg = lane >> 4;
    const int m0 = (wave & 3) * 16;
    const int slot = wave >> 2;              // 0..1
    ushort* stg = s_stage + wave * 2048;     // wave-private 4 KB

    // Wemb fragments hoisted to registers (L2-resident, read once)
    short8 wembR[8];
    #pragma unroll
    for (int nt = 0; nt < 8; ++nt)
        wembR[nt] = *(const short8*)(Wembc + nt*512 + lane*8);

    const f32x4 zero = {0.f, 0.f, 0.f, 0.f};

    for (int it = 0; it < 4; ++it) {
        const int bA = blockIdx.x*16 + slot*8 + it*2;
        const int bB = bA + 1;

        // ---- G1 (swapped): h1T = Wemb @ xn^T ; bias folded via col31 ----
        const short8 xA = *(const short8*)(xnB + ((size_t)bA*NK + m0 + lr)*32 + 8*lg);
        const short8 xB = *(const short8*)(xnB + ((size_t)bB*NK + m0 + lr)*32 + 8*lg);
        f32x4 h1A[8], h1B[8];
        #pragma unroll
        for (int nt = 0; nt < 8; ++nt) {
            h1A[nt] = mfma32(wembR[nt], xA, zero);
            h1B[nt] = mfma32(wembR[nt], xB, zero);
        }

        // ---- LN1: relu + stats over n (lane-local 32 + 2 shuffles) ----
        float psA=0.f, pqA=0.f, psB=0.f, pqB=0.f;
        #pragma unroll
        for (int nt = 0; nt < 8; ++nt)
            #pragma unroll
            for (int r = 0; r < 4; ++r) {
                float a = fmaxf(h1A[nt][r], 0.f); h1A[nt][r] = a; psA += a; pqA += a*a;
                float c = fmaxf(h1B[nt][r], 0.f); h1B[nt][r] = c; psB += c; pqB += c*c;
            }
        #pragma unroll
        for (int m = 16; m <= 32; m <<= 1) {
            psA += __shfl_xor(psA, m, 64); pqA += __shfl_xor(pqA, m, 64);
            psB += __shfl_xor(psB, m, 64); pqB += __shfl_xor(pqB, m, 64);
        }
        const float muA = psA*(1.f/128.f), muB = psB*(1.f/128.f);
        const float rsA = rsqrtf(pqA*(1.f/128.f) - muA*muA + 1e-5f);
        const float rsB = rsqrtf(pqB*(1.f/128.f) - muB*muB + 1e-5f);

        // ---- affine + pack to bf16 (these ARE the G2 B-fragments) ----
        short4v h1pA[8], h1pB[8];
        #pragma unroll
        for (int nt = 0; nt < 8; ++nt) {
            const float4 g = *(const float4*)(ln1g + nt*16 + 4*lg);
            const float4 bb = *(const float4*)(ln1b + nt*16 + 4*lg);
            const float gr[4] = {g.x, g.y, g.z, g.w};
            const float br[4] = {bb.x, bb.y, bb.z, bb.w};
            #pragma unroll
            for (int r = 0; r < 4; ++r) {
                h1pA[nt][r] = (short)f2bf((h1A[nt][r]-muA)*rsA*gr[r] + br[r]);
                h1pB[nt][r] = (short)f2bf((h1B[nt][r]-muB)*rsB*gr[r] + br[r]);
            }
        }

        // ---- G2 (chunks of 4 n2-tiles) feeding G3 accumulation ----
        f32x4 acc3A[8], acc3B[8];
        #pragma unroll
        for (int nt3 = 0; nt3 < 8; ++nt3) {
            const float4 bb = *(const float4*)(b2 + nt3*16 + 4*lg);
            acc3A[nt3] = f32x4{bb.x, bb.y, bb.z, bb.w};
            acc3B[nt3] = f32x4{bb.x, bb.y, bb.z, bb.w};
        }
        #pragma unroll
        for (int ck = 0; ck < 4; ++ck) {
            short4v h2pA[4], h2pB[4];
            #pragma unroll
            for (int j = 0; j < 4; ++j) {
                const int nt2 = ck*4 + j;
                const float4 bb = *(const float4*)(b1 + nt2*16 + 4*lg);
                f32x4 a2A = f32x4{bb.x, bb.y, bb.z, bb.w};
                f32x4 a2B = a2A;
                #pragma unroll
                for (int kt = 0; kt < 8; ++kt) {
                    const short4v w = *(const short4v*)(s_w1 + (nt2*8 + kt)*256 + lane*4);
                    a2A = mfma16(w, h1pA[kt], a2A);
                    a2B = mfma16(w, h1pB[kt], a2B);
                }
                #pragma unroll
                for (int r = 0; r < 4; ++r) {
                    h2pA[j][r] = (short)f2bf(fmaxf(a2A[r], 0.f));
                    h2pB[j][r] = (short)f2bf(fmaxf(a2B[r], 0.f));
                }
            }
            #pragma unroll
            for (int nt3 = 0; nt3 < 8; ++nt3)
                #pragma unroll
                for (int j = 0; j < 4; ++j) {
                    const short4v w = *(const short4v*)(s_w2 + (nt3*16 + ck*4 + j)*256 + lane*4);
                    acc3A[nt3] = mfma16(w, h2pA[j], acc3A[nt3]);
                    acc3B[nt3] = mfma16(w, h2pB[j], acc3B[nt3]);
                }
        }

        // ---- residual + LN2 stats (T layout) ----
        const float keepA = 1.f - outmask[(size_t)bA*NK + m0 + lr];
        const float keepB = 1.f - outmask[(size_t)bB*NK + m0 + lr];
        psA=0.f; pqA=0.f; psB=0.f; pqB=0.f;
        #pragma unroll
        for (int nt = 0; nt < 8; ++nt)
            #pragma unroll
            for (int r = 0; r < 4; ++r) {
                const float qA = bf2f((ushort)h1pA[nt][r]) + fmaxf(acc3A[nt][r], 0.f);
                const float qB = bf2f((ushort)h1pB[nt][r]) + fmaxf(acc3B[nt][r], 0.f);
                acc3A[nt][r] = qA; psA += qA; pqA += qA*qA;
                acc3B[nt][r] = qB; psB += qB; pqB += qB*qB;
            }
        #pragma unroll
        for (int m = 16; m <= 32; m <<= 1) {
            psA += __shfl_xor(psA, m, 64); pqA += __shfl_xor(pqA, m, 64);
            psB += __shfl_xor(psB, m, 64); pqB += __shfl_xor(pqB, m, 64);
        }
        const float mA = psA*(1.f/128.f), mB = psB*(1.f/128.f);
        const float rA = rsqrtf(pqA*(1.f/128.f) - mA*mA + 1e-5f);
        const float rB = rsqrtf(pqB*(1.f/128.f) - mB*mB + 1e-5f);

        // ---- egress: LN2 affine -> bf16 -> wave-private LDS -> coalesced f32 store ----
        // batch A
        #pragma unroll
        for (int nt = 0; nt < 8; ++nt) {
            const float4 g = *(const float4*)(ln2g + nt*16 + 4*lg);
            const float4 bb = *(const float4*)(ln2b + nt*16 + 4*lg);
            const float o0 = ((acc3A[nt][0]-mA)*rA*g.x + bb.x)*keepA;
            const float o1 = ((acc3A[nt][1]-mA)*rA*g.y + bb.y)*keepA;
            const float o2 = ((acc3A[nt][2]-mA)*rA*g.z + bb.z)*keepA;
            const float o3 = ((acc3A[nt][3]-mA)*rA*g.w + bb.w)*keepA;
            uint2 pk;
            pk.x = (unsigned)f2bf(o0) | ((unsigned)f2bf(o1) << 16);
            pk.y = (unsigned)f2bf(o2) | ((unsigned)f2bf(o3) << 16);
            const int byte = (lr*256 + nt*32 + lg*8) ^ ((lr & 7) << 4);
            *reinterpret_cast<uint2*>((char*)stg + byte) = pk;
        }
        asm volatile("s_waitcnt lgkmcnt(0)" ::: "memory");
        #pragma unroll
        for (int q = 0; q < 4; ++q) {
            const int s = q*4 + lg;
            const int byte = (s*256 + lr*16) ^ ((s & 7) << 4);
            const short8 v = *reinterpret_cast<const short8*>((const char*)stg + byte);
            float4 w0, w1;
            w0.x = bf2f((ushort)v[0]); w0.y = bf2f((ushort)v[1]);
            w0.z = bf2f((ushort)v[2]); w0.w = bf2f((ushort)v[3]);
            w1.x = bf2f((ushort)v[4]); w1.y = bf2f((ushort)v[5]);
            w1.z = bf2f((ushort)v[6]); w1.w = bf2f((ushort)v[7]);
            float* dst = out + ((size_t)bA*NK + m0 + s)*DM + lr*8;
            *reinterpret_cast<float4*>(dst)     = w0;
            *reinterpret_cast<float4*>(dst + 4) = w1;
        }
        asm volatile("s_waitcnt lgkmcnt(0)" ::: "memory");
        // batch B
        #pragma unroll
        for (int nt = 0; nt < 8; ++nt) {
            const float4 g = *(const float4*)(ln2g + nt*16 + 4*lg);
            const float4 bb = *(const float4*)(ln2b + nt*16 + 4*lg);
            const float o0 = ((acc3B[nt][0]-mB)*rB*g.x + bb.x)*keepB;
            const float o1 = ((acc3B[nt][1]-mB)*rB*g.y + bb.y)*keepB;
            const float o2 = ((acc3B[nt][2]-mB)*rB*g.z + bb.z)*keepB;
            const float o3 = ((acc3B[nt][3]-mB)*rB*g.w + bb.w)*keepB;
            uint2 pk;
            pk.x = (unsigned)f2bf(o0) | ((unsigned)f2bf(o1) << 16);
            pk.y = (unsigned)f2bf(o2) | ((unsigned)f2bf(o3) << 16);
            const int byte = (lr*256 + nt*32 + lg*8) ^ ((lr & 7) << 4);
            *reinterpret_cast<uint2*>((char*)stg + byte) = pk;
        }
        asm volatile("s_waitcnt lgkmcnt(0)" ::: "memory");
        #pragma unroll
        for (int q = 0; q < 4; ++q) {
            const int s = q*4 + lg;
            const int byte = (s*256 + lr*16) ^ ((s & 7) << 4);
            const short8 v = *reinterpret_cast<const short8*>((const char*)stg + byte);
            float4 w0, w1;
            w0.x = bf2f((ushort)v[0]); w0.y = bf2f((ushort)v[1]);
            w0.z = bf2f((ushort)v[2]); w0.w = bf2f((ushort)v[3]);
            w1.x = bf2f((ushort)v[4]); w1.y = bf2f((ushort)v[5]);
            w1.z = bf2f((ushort)v[6]); w1.w = bf2f((ushort)v[7]);
            float* dst = out + ((size_t)bB*NK + m0 + s)*DM + lr*8;
            *reinterpret_cast<float4*>(dst)     = w0;
            *reinterpret_cast<float4*>(dst + 4) = w1;
        }
        asm volatile("s_waitcnt lgkmcnt(0)" ::: "memory");
    }
}

extern "C" void kernel_launch(void* const* d_in, const int* in_sizes, int n_in,
                              void* d_out, int out_size, void* d_ws, size_t ws_size,
                              hipStream_t stream) {
    const float* x        = (const float*)d_in[0];
    const int*   idxs     = (const int*)  d_in[1];
    const float* origin   = (const float*)d_in[2];
    const float* direction= (const float*)d_in[3];
    const float* ncount   = (const float*)d_in[4];
    const float* nmean    = (const float*)d_in[5];
    const float* nsq      = (const float*)d_in[6];
    const float* W_emb    = (const float*)d_in[7];
    const float* b_emb    = (const float*)d_in[8];
    const float* ln1g     = (const float*)d_in[9];
    const float* ln1b     = (const float*)d_in[10];
    const float* W1       = (const float*)d_in[11];
    const float* b1       = (const float*)d_in[12];
    const float* W2       = (const float*)d_in[13];
    const float* b2       = (const float*)d_in[14];
    const float* ln2g     = (const float*)d_in[15];
    const float* ln2b     = (const float*)d_in[16];

    float* out     = (float*)d_out;
    float* outrel  = out    + (size_t)NB*NK*DM;
    float* outmask = outrel + (size_t)NB*NK*2;

    ushort* Wembc = (ushort*)d_ws;              // 4096
    ushort* W1c   = Wembc + 4096;               // 32768
    ushort* W2c   = W1c   + 32768;              // 32768
    ushort* xnB   = W2c   + 32768;              // 4096*64*32 (16 MB)

    convert_weights<<<128, 256, 0, stream>>>(W_emb, b_emb, W1, W2, Wembc, W1c, W2c);
    select_kernel<<<NB, 256, 0, stream>>>(x, idxs, origin, direction, ncount,
        nmean, nsq, xnB, outrel, outmask);
    mlp_kernel<<<256, 512, 0, stream>>>(b1, b2, ln1g, ln1b, ln2g, ln2b,
        Wembc, W1c, W2c, xnB, outmask, out);
}

// Round 8
// 404.794 us; speedup vs baseline: 1.8812x; 1.8812x over previous
//
#include <hip/hip_runtime.h>
#include <math.h>

#define NB 4096
#define NN 256
#define NF 16
#define NK 64
#define DIN 19
#define DM 128
#define DFF 256

using short8  = __attribute__((ext_vector_type(8))) short;
using short4v = __attribute__((ext_vector_type(4))) short;
using f32x4   = __attribute__((ext_vector_type(4))) float;

__device__ inline f32x4 mfma32(short8 a, short8 b, f32x4 c) {
    return __builtin_amdgcn_mfma_f32_16x16x32_bf16(a, b, c, 0, 0, 0);
}
__device__ inline f32x4 mfma16(short4v a, short4v b, f32x4 c) {
    return __builtin_amdgcn_mfma_f32_16x16x16bf16_1k(a, b, c, 0, 0, 0);
}

__device__ inline ushort f2bf(float f) {
    unsigned u = __float_as_uint(f);
    return (ushort)((u + 0x7fffu + ((u >> 16) & 1u)) >> 16);
}
__device__ inline float bf2f(ushort h) {
    return __uint_as_float(((unsigned)h) << 16);
}

// ---- pre-kernel: convert + PERMUTE weights so fragment reads are contiguous ----
// Wembc: per nt (8): 64 lanes x 8 shorts; lane: n=nt*16+(lane&15), k=(lane>>4)*8+j
//        (K padded 19->32; col 31 = b_emb  [bias folded via xn col31=1.0])
// W1c:   per grp=(nt2*8+kt): 64 lanes x 4 shorts: n1=nt2*16+(lane&15), k1=kt*16+(lane>>4)*4+e
// W2c:   per grp=(nt3*16+kt3): n2=nt3*16+(lane&15), k2=kt3*16+(lane>>4)*4+e
__global__ void convert_weights(const float* __restrict__ W_emb,
                                const float* __restrict__ b_emb,
                                const float* __restrict__ W1,
                                const float* __restrict__ W2,
                                ushort* __restrict__ Wembc,
                                ushort* __restrict__ W1c,
                                ushort* __restrict__ W2c) {
    const int i = blockIdx.x * 256 + threadIdx.x;   // 0..32767
    if (i < 4096) {
        const int j = i & 7, s = i >> 3;
        const int nt = s >> 6, lane = s & 63;
        const int n = nt*16 + (lane & 15);
        const int k = (lane >> 4)*8 + j;
        float v = (k < DIN) ? W_emb[n*DIN + k] : (k == 31 ? b_emb[n] : 0.0f);
        Wembc[i] = f2bf(v);
    }
    if (i < 32768) {
        const int e = i & 3, s = i >> 2;
        const int grp = s >> 6, lane = s & 63;
        const int lr = lane & 15, lg = lane >> 4;
        const int n1 = (grp >> 3)*16 + lr;
        const int k1 = (grp & 7)*16 + lg*4 + e;
        W1c[i] = f2bf(W1[n1*DM + k1]);
        const int n2 = (grp >> 4)*16 + lr;
        const int k2 = (grp & 15)*16 + lg*4 + e;
        W2c[i] = f2bf(W2[n2*DFF + k2]);
    }
}

// ---- kernel 1: top-K select + feature build ----
__global__ __launch_bounds__(256) void select_kernel(
    const float* __restrict__ x, const int* __restrict__ idxs,
    const float* __restrict__ origin, const float* __restrict__ direction,
    const float* __restrict__ norm_count, const float* __restrict__ norm_mean,
    const float* __restrict__ norm_sqsum,
    ushort* __restrict__ xnB, float* __restrict__ outrel, float* __restrict__ outmask)
{
    __shared__ unsigned long long s_keys[NN];
    const int b = blockIdx.x;
    const int t = threadIdx.x;

    const float dirx = direction[b*2+0], diry = direction[b*2+1];
    const float ang = -atan2f(diry, dirx);
    const float cr = cosf(ang), sr = sinf(ang);
    const float ox = origin[b*2+0], oy = origin[b*2+1];

    {
        const int j = idxs[b*NN + t];
        const float4 xr = *reinterpret_cast<const float4*>(x + (size_t)j*NF);
        const float dx = xr.x - ox, dy = xr.y - oy;
        const float r0 = cr*dx - sr*dy;
        const float r1 = sr*dx + cr*dy;
        const float dist = sqrtf(r0*r0 + r1*r1);
        const float key = -dist - ((xr.z == 0.0f) ? 1e8f : 0.0f);
        unsigned u = __float_as_uint(key);
        u = (u & 0x80000000u) ? ~u : (u | 0x80000000u);
        s_keys[t] = ((unsigned long long)(~u) << 32) | (unsigned)t;
    }
    __syncthreads();

    for (int sz = 2; sz <= NN; sz <<= 1) {
        for (int st = sz >> 1; st > 0; st >>= 1) {
            const int ixj = t ^ st;
            if (ixj > t) {
                const unsigned long long a = s_keys[t];
                const unsigned long long c = s_keys[ixj];
                const bool up = ((t & sz) == 0);
                if ((a > c) == up) { s_keys[t] = c; s_keys[ixj] = a; }
            }
            __syncthreads();
        }
    }

    if (t < NK) {
        const int p = (int)(s_keys[t] & 0xFFFFFFFFull);
        const int j = idxs[b*NN + p];
        const float4* xrow = reinterpret_cast<const float4*>(x + (size_t)j*NF);
        const float4 a0 = xrow[0], a1 = xrow[1], a2 = xrow[2], a3 = xrow[3];
        float xc[DIN];
        xc[0]=a0.x; xc[1]=a0.y; xc[2]=a0.z; xc[3]=a0.w;
        xc[4]=a1.x; xc[5]=a1.y; xc[6]=a1.z; xc[7]=a1.w;
        xc[8]=a2.x; xc[9]=a2.y; xc[10]=a2.z; xc[11]=a2.w;
        xc[12]=a3.x; xc[13]=a3.y; xc[14]=a3.z; xc[15]=a3.w;
        const float dx = xc[0]-ox, dy = xc[1]-oy;
        const float r0 = cr*dx - sr*dy;
        const float r1 = sr*dx + cr*dy;
        const float dist = sqrtf(r0*r0 + r1*r1);
        const float inv = 1.0f / (dist + 1e-8f);
        xc[16] = r0*inv; xc[17] = r1*inv; xc[18] = sqrtf(dist);
        const float cnt = norm_count[0];
        union { ushort us[32]; int4 v4[4]; } u;
        #pragma unroll
        for (int f = 0; f < DIN; ++f) {
            float sd = sqrtf(norm_sqsum[f] / (cnt - 1.0f));
            sd = (sd == 0.0f) ? 1.0f : sd;
            float v = (xc[f] - norm_mean[f]) / sd;
            v = fminf(fmaxf(v, -5.0f), 5.0f);
            u.us[f] = f2bf(v);
        }
        #pragma unroll
        for (int f = DIN; f < 31; ++f) u.us[f] = 0;
        u.us[31] = 0x3F80;   // 1.0 bf16 -> bias column
        int4* dst = reinterpret_cast<int4*>(xnB + ((size_t)b*NK + t)*32);
        dst[0] = u.v4[0]; dst[1] = u.v4[1]; dst[2] = u.v4[2]; dst[3] = u.v4[3];
        const bool msk = (xc[2] == 0.0f);
        outrel[((size_t)b*NK + t)*2 + 0] = r0;
        outrel[((size_t)b*NK + t)*2 + 1] = r1;
        outmask[(size_t)b*NK + t] = msk ? 1.0f : 0.0f;
    }
}

// ---- kernel 2: all-register transposed MLP, 256 threads (4 waves, 1 wave/EU) ----
// 256-thread block => 1 wave/EU => full 512-reg budget per wave => NO SPILL
// (R5-R7's 512-thread blocks capped arch-VGPR at 128 -> GB-scale spill traffic).
__global__ __launch_bounds__(256, 1) void mlp_kernel(
    const float* __restrict__ b1, const float* __restrict__ b2,
    const float* __restrict__ ln1g, const float* __restrict__ ln1b,
    const float* __restrict__ ln2g, const float* __restrict__ ln2b,
    const ushort* __restrict__ Wembc, const ushort* __restrict__ W1c,
    const ushort* __restrict__ W2c, const ushort* __restrict__ xnB,
    const float* __restrict__ outmask, float* __restrict__ out)
{
    __shared__ __align__(16) ushort s_w1[32768];     // 64 KB
    __shared__ __align__(16) ushort s_w2[32768];     // 64 KB -> 128 KB, 1 block/CU

    const int t = threadIdx.x;
    {
        const int4* g1 = (const int4*)W1c;  int4* d1 = (int4*)s_w1;
        const int4* g2 = (const int4*)W2c;  int4* d2 = (int4*)s_w2;
        #pragma unroll
        for (int j = 0; j < 16; ++j) { d1[j*256 + t] = g1[j*256 + t];
                                       d2[j*256 + t] = g2[j*256 + t]; }
    }
    __syncthreads();

    const int wave = t >> 6, lane = t & 63;
    const int lr = lane & 15, lg = lane >> 4;
    const int m0 = wave * 16;

    // Wemb fragments hoisted to registers (L2-resident, read once)
    short8 wembR[8];
    #pragma unroll
    for (int nt = 0; nt < 8; ++nt)
        wembR[nt] = *(const short8*)(Wembc + nt*512 + lane*8);

    const f32x4 zero = {0.f, 0.f, 0.f, 0.f};

    for (int it = 0; it < 8; ++it) {
        const int bA = blockIdx.x*16 + it*2;
        const int bB = bA + 1;

        // ---- G1 (swapped): h1T = Wemb @ xn^T ; bias folded via col31 ----
        const short8 xA = *(const short8*)(xnB + ((size_t)bA*NK + m0 + lr)*32 + 8*lg);
        const short8 xB = *(const short8*)(xnB + ((size_t)bB*NK + m0 + lr)*32 + 8*lg);
        f32x4 h1A[8], h1B[8];
        #pragma unroll
        for (int nt = 0; nt < 8; ++nt) {
            h1A[nt] = mfma32(wembR[nt], xA, zero);
            h1B[nt] = mfma32(wembR[nt], xB, zero);
        }

        // ---- LN1: relu + stats over n (lane-local 32 + 2 shuffles) ----
        float psA=0.f, pqA=0.f, psB=0.f, pqB=0.f;
        #pragma unroll
        for (int nt = 0; nt < 8; ++nt)
            #pragma unroll
            for (int r = 0; r < 4; ++r) {
                float a = fmaxf(h1A[nt][r], 0.f); h1A[nt][r] = a; psA += a; pqA += a*a;
                float c = fmaxf(h1B[nt][r], 0.f); h1B[nt][r] = c; psB += c; pqB += c*c;
            }
        #pragma unroll
        for (int m = 16; m <= 32; m <<= 1) {
            psA += __shfl_xor(psA, m, 64); pqA += __shfl_xor(pqA, m, 64);
            psB += __shfl_xor(psB, m, 64); pqB += __shfl_xor(pqB, m, 64);
        }
        const float muA = psA*(1.f/128.f), muB = psB*(1.f/128.f);
        const float rsA = rsqrtf(pqA*(1.f/128.f) - muA*muA + 1e-5f);
        const float rsB = rsqrtf(pqB*(1.f/128.f) - muB*muB + 1e-5f);

        // ---- affine + pack to bf16 (these ARE the G2 B-fragments) ----
        short4v h1pA[8], h1pB[8];
        #pragma unroll
        for (int nt = 0; nt < 8; ++nt) {
            const float4 g = *(const float4*)(ln1g + nt*16 + 4*lg);
            const float4 bb = *(const float4*)(ln1b + nt*16 + 4*lg);
            const float gr[4] = {g.x, g.y, g.z, g.w};
            const float br[4] = {bb.x, bb.y, bb.z, bb.w};
            #pragma unroll
            for (int r = 0; r < 4; ++r) {
                h1pA[nt][r] = (short)f2bf((h1A[nt][r]-muA)*rsA*gr[r] + br[r]);
                h1pB[nt][r] = (short)f2bf((h1B[nt][r]-muB)*rsB*gr[r] + br[r]);
            }
        }

        // ---- G2 (chunks of 4 n2-tiles) feeding G3 accumulation ----
        f32x4 acc3A[8], acc3B[8];
        #pragma unroll
        for (int nt3 = 0; nt3 < 8; ++nt3) {
            const float4 bb = *(const float4*)(b2 + nt3*16 + 4*lg);
            acc3A[nt3] = f32x4{bb.x, bb.y, bb.z, bb.w};
            acc3B[nt3] = f32x4{bb.x, bb.y, bb.z, bb.w};
        }
        #pragma unroll
        for (int ck = 0; ck < 4; ++ck) {
            short4v h2pA[4], h2pB[4];
            #pragma unroll
            for (int j = 0; j < 4; ++j) {
                const int nt2 = ck*4 + j;
                const float4 bb = *(const float4*)(b1 + nt2*16 + 4*lg);
                f32x4 a2A = f32x4{bb.x, bb.y, bb.z, bb.w};
                f32x4 a2B = a2A;
                #pragma unroll
                for (int kt = 0; kt < 8; ++kt) {
                    const short4v w = *(const short4v*)(s_w1 + (nt2*8 + kt)*256 + lane*4);
                    a2A = mfma16(w, h1pA[kt], a2A);
                    a2B = mfma16(w, h1pB[kt], a2B);
                }
                #pragma unroll
                for (int r = 0; r < 4; ++r) {
                    h2pA[j][r] = (short)f2bf(fmaxf(a2A[r], 0.f));
                    h2pB[j][r] = (short)f2bf(fmaxf(a2B[r], 0.f));
                }
            }
            #pragma unroll
            for (int nt3 = 0; nt3 < 8; ++nt3)
                #pragma unroll
                for (int j = 0; j < 4; ++j) {
                    const short4v w = *(const short4v*)(s_w2 + (nt3*16 + ck*4 + j)*256 + lane*4);
                    acc3A[nt3] = mfma16(w, h2pA[j], acc3A[nt3]);
                    acc3B[nt3] = mfma16(w, h2pB[j], acc3B[nt3]);
                }
        }

        // ---- residual + LN2 stats (T layout) ----
        const float keepA = 1.f - outmask[(size_t)bA*NK + m0 + lr];
        const float keepB = 1.f - outmask[(size_t)bB*NK + m0 + lr];
        psA=0.f; pqA=0.f; psB=0.f; pqB=0.f;
        #pragma unroll
        for (int nt = 0; nt < 8; ++nt)
            #pragma unroll
            for (int r = 0; r < 4; ++r) {
                const float qA = bf2f((ushort)h1pA[nt][r]) + fmaxf(acc3A[nt][r], 0.f);
                const float qB = bf2f((ushort)h1pB[nt][r]) + fmaxf(acc3B[nt][r], 0.f);
                acc3A[nt][r] = qA; psA += qA; pqA += qA*qA;
                acc3B[nt][r] = qB; psB += qB; pqB += qB*qB;
            }
        #pragma unroll
        for (int m = 16; m <= 32; m <<= 1) {
            psA += __shfl_xor(psA, m, 64); pqA += __shfl_xor(pqA, m, 64);
            psB += __shfl_xor(psB, m, 64); pqB += __shfl_xor(pqB, m, 64);
        }
        const float mA = psA*(1.f/128.f), mB = psB*(1.f/128.f);
        const float rA = rsqrtf(pqA*(1.f/128.f) - mA*mA + 1e-5f);
        const float rB = rsqrtf(pqB*(1.f/128.f) - mB*mB + 1e-5f);

        // ---- LN2 affine + mask + store (per (row,nt): lanes lg=0..3 cover one
        //      full 64B line -> fully-coalesced write, no RFO amplification) ----
        #pragma unroll
        for (int nt = 0; nt < 8; ++nt) {
            const float4 g = *(const float4*)(ln2g + nt*16 + 4*lg);
            const float4 bb = *(const float4*)(ln2b + nt*16 + 4*lg);
            float4 oA, oB;
            oA.x = ((acc3A[nt][0]-mA)*rA*g.x + bb.x)*keepA;
            oA.y = ((acc3A[nt][1]-mA)*rA*g.y + bb.y)*keepA;
            oA.z = ((acc3A[nt][2]-mA)*rA*g.z + bb.z)*keepA;
            oA.w = ((acc3A[nt][3]-mA)*rA*g.w + bb.w)*keepA;
            oB.x = ((acc3B[nt][0]-mB)*rB*g.x + bb.x)*keepB;
            oB.y = ((acc3B[nt][1]-mB)*rB*g.y + bb.y)*keepB;
            oB.z = ((acc3B[nt][2]-mB)*rB*g.z + bb.z)*keepB;
            oB.w = ((acc3B[nt][3]-mB)*rB*g.w + bb.w)*keepB;
            *(float4*)(out + ((size_t)bA*NK + m0 + lr)*DM + nt*16 + 4*lg) = oA;
            *(float4*)(out + ((size_t)bB*NK + m0 + lr)*DM + nt*16 + 4*lg) = oB;
        }
    }
}

extern "C" void kernel_launch(void* const* d_in, const int* in_sizes, int n_in,
                              void* d_out, int out_size, void* d_ws, size_t ws_size,
                              hipStream_t stream) {
    const float* x        = (const float*)d_in[0];
    const int*   idxs     = (const int*)  d_in[1];
    const float* origin   = (const float*)d_in[2];
    const float* direction= (const float*)d_in[3];
    const float* ncount   = (const float*)d_in[4];
    const float* nmean    = (const float*)d_in[5];
    const float* nsq      = (const float*)d_in[6];
    const float* W_emb    = (const float*)d_in[7];
    const float* b_emb    = (const float*)d_in[8];
    const float* ln1g     = (const float*)d_in[9];
    const float* ln1b     = (const float*)d_in[10];
    const float* W1       = (const float*)d_in[11];
    const float* b1       = (const float*)d_in[12];
    const float* W2       = (const float*)d_in[13];
    const float* b2       = (const float*)d_in[14];
    const float* ln2g     = (const float*)d_in[15];
    const float* ln2b     = (const float*)d_in[16];

    float* out     = (float*)d_out;
    float* outrel  = out    + (size_t)NB*NK*DM;
    float* outmask = outrel + (size_t)NB*NK*2;

    ushort* Wembc = (ushort*)d_ws;              // 4096
    ushort* W1c   = Wembc + 4096;               // 32768
    ushort* W2c   = W1c   + 32768;              // 32768
    ushort* xnB   = W2c   + 32768;              // 4096*64*32 (16 MB)

    convert_weights<<<128, 256, 0, stream>>>(W_emb, b_emb, W1, W2, Wembc, W1c, W2c);
    select_kernel<<<NB, 256, 0, stream>>>(x, idxs, origin, direction, ncount,
        nmean, nsq, xnB, outrel, outmask);
    mlp_kernel<<<256, 256, 0, stream>>>(b1, b2, ln1g, ln1b, ln2g, ln2b,
        Wembc, W1c, W2c, xnB, outmask, out);
}